// Round 5
// baseline (1044.825 us; speedup 1.0000x reference)
//
#include <hip/hip_runtime.h>
#include <hip/hip_bf16.h>
#include <math.h>

typedef unsigned short u16;
typedef unsigned int u32;
typedef _Float16 f16;
typedef _Float16 f16x8 __attribute__((ext_vector_type(8)));
typedef float f32x4 __attribute__((ext_vector_type(4)));

// ---------------- constants ----------------
#define BATCH 32
#define CIN   1024
#define COUT  512
#define NPOS  8192
#define K9    9216
#define KHALF 4608
#define TOPK  30
#define NROI  960
#define POOLN 7
#define IMG   256

// ---------------- ws layout (float units) ----------------
#define O_XP0  0ull
#define O_XP1  4194304ull
#define O_CH   8388608ull      // u16[8388608]
#define O_CL   12582912ull
#define O_WH   16777216ull     // u16[4718592]
#define O_WL   19136512ull
#define O_Z    21495808ull     // 512 u16 zeros
#define O_HW   21496064ull
#define O_SC   21519104ull
#define O_RG   21592832ull
#define O_ROI  21887744ull
#define O_VAL  21891584ull
#define O_LAB  21892544ull
#define WS_FLOATS 21893504ull
// overlays on XP0 region (used after heads consumed XP0/XP1):
#define O_NF   1474560ull
#define O_RL   1720320ull
#define O_RA   1721280ull

// async global->LDS, 16 bytes/lane, LDS dest = wave-uniform base + lane*16
__device__ __forceinline__ void gl_lds16(const void* g, void* l) {
    __builtin_amdgcn_global_load_lds(
        (const __attribute__((address_space(1))) u32*)g,
        (__attribute__((address_space(3))) u32*)l,
        16, 0, 0);
}

// ---------------- fp16 hi/lo split ----------------
__device__ inline void split16(float x, u16& h, u16& l) {
    f16 hv = (f16)x;
    f16 lv = (f16)(x - (float)hv);
    h = *(u16*)&hv;
    l = *(u16*)&lv;
}

// ---------------- fused prep: clip convert + w convert + zeros + hw repack ----------------
#define NB_CLIP 8192
#define NB_W    18432
#define NB_Z    1
#define NB_HW   90
__global__ __launch_bounds__(256)
void convert_all(const float* __restrict__ clip, const float* __restrict__ conv_w,
                 const float* __restrict__ cls_w, const float* __restrict__ reg_w,
                 u16* __restrict__ CH, u16* __restrict__ CL,
                 u16* __restrict__ WH, u16* __restrict__ WL,
                 u16* __restrict__ Z, float* __restrict__ HW) {
    int bid = blockIdx.x, t = threadIdx.x;
    if (bid < NB_CLIP) {
        int tid = bid * 256 + t;
        int c4  = (tid & 255) * 4;
        int pos = (tid >> 8) & 255;
        int b   = tid >> 16;
        float4 v = *(const float4*)(clip + ((size_t)(1 + pos) * 32 + b) * 1024 + c4);
        float xs[4] = {v.x, v.y, v.z, v.w};
        ushort4 hh, ll;
        u16* hp = (u16*)&hh; u16* lp = (u16*)&ll;
#pragma unroll
        for (int q = 0; q < 4; ++q) split16(xs[q], hp[q], lp[q]);
        size_t o = ((size_t)(b * 256 + pos)) * 1024 + c4;
        *(ushort4*)(CH + o) = hh;
        *(ushort4*)(CL + o) = ll;
    } else if (bid < NB_CLIP + NB_W) {
        int bid2 = bid - NB_CLIP;
        int k = (bid2 % 36) * 256 + t;
        int o = bid2 / 36;
        int c = k & 1023, p = k >> 10;
        float x = conv_w[(size_t)o * K9 + c * 9 + p];
        u16 h, l;
        split16(x, h, l);
        WH[(size_t)o * K9 + k] = h;
        WL[(size_t)o * K9 + k] = l;
    } else if (bid < NB_CLIP + NB_W + NB_Z) {
        Z[t] = 0; Z[256 + t] = 0;
    } else {
        int tid2 = (bid - NB_CLIP - NB_W - NB_Z) * 256 + t;
        if (tid2 < 45 * 512) {
            int c = tid2 / 45, a = tid2 % 45;
            HW[tid2] = (a < 9) ? cls_w[a * 512 + c] : reg_w[(a - 9) * 512 + c];
        }
    }
}

// ---------------- MFMA conv GEMM (fp16x2 split, 3 MFMA/product) ----------------
// TM=128, TN=64, grid = 64 mb x 8 nb x 2 ks = 1024 blocks (4/CU).
// gid: nb = gid&7, ks = (gid>>3)&1, mb = gid>>4. XCD = gid%8 = nb -> each XCD's
// B slice (64 rows x 9216 x 2B x 2 arrays = 2.36 MB) fits its 4 MB L2.
// Per-output accumulation order is bit-identical to round 4 (same 32-k windows
// ascending, same 3-MFMA sequence) -> X bit-exact, discrete decisions unchanged.
__global__ __launch_bounds__(256, 4)
void conv_mfma(const u16* __restrict__ CH, const u16* __restrict__ CL,
               const u16* __restrict__ WH, const u16* __restrict__ WL,
               const u16* __restrict__ ZS,
               float* __restrict__ XP0, float* __restrict__ XP1) {
    __shared__ __align__(16) u16 Ah[4096];   // 128 rows x 32 k; slot s of row r holds granule s^((r>>1)&3)
    __shared__ __align__(16) u16 Al[4096];
    __shared__ __align__(16) u16 Bh[2048];   // 64 rows x 32 k
    __shared__ __align__(16) u16 Bl[2048];

    const int t = threadIdx.x;
    const int gid = blockIdx.x;
    const int nb = gid & 7;
    const int ks = (gid >> 3) & 1;
    const int mb = gid >> 4;
    const int ksOff = ks * KHALF;
    float* __restrict__ XP = ks ? XP1 : XP0;

    const int wave = t >> 6, lane = t & 63;

    // A staging: wave w, call j (0/1): lane covers row r = w*32 + j*16 + lane/4,
    // physical slot s = lane&3, data granule q = s ^ ((r>>1)&3)
    int qA[2], siA[2], sjA[2], bA[2];
#pragma unroll
    for (int j = 0; j < 2; ++j) {
        int r = wave * 32 + j * 16 + (lane >> 2);
        int s = lane & 3;
        qA[j] = s ^ ((r >> 1) & 3);
        int m = mb * 128 + r;
        bA[j] = m >> 8;
        int ij = m & 255;
        siA[j] = ij >> 4; sjA[j] = ij & 15;
    }
    // B staging: wave w covers rows w*16 .. w*16+16 (one call)
    const int rB = wave * 16 + (lane >> 2);
    const int qB = (lane & 3) ^ ((rB >> 1) & 3);
    const u16* srcBh = WH + (size_t)(nb * 64 + rB) * K9 + qB * 8;
    const u16* srcBl = WL + (size_t)(nb * 64 + rB) * K9 + qB * 8;

    // compute ids: wave tile 64m x 32n
    const int wm = wave >> 1, wn = wave & 1;
    const int l16 = lane & 15, quad = lane >> 4;
    int offA[4], offB[2];                       // u16 indices into LDS
#pragma unroll
    for (int q = 0; q < 4; ++q) {
        int ar = wm * 64 + q * 16 + l16;
        offA[q] = ar * 32 + ((quad ^ ((ar >> 1) & 3)) << 3);
    }
#pragma unroll
    for (int q = 0; q < 2; ++q) {
        int br = wn * 32 + q * 16 + l16;
        offB[q] = br * 32 + ((quad ^ ((br >> 1) & 3)) << 3);
    }

    f32x4 acc[4][2];
#pragma unroll
    for (int r = 0; r < 4; ++r)
#pragma unroll
        for (int c = 0; c < 2; ++c) acc[r][c] = (f32x4){0.f, 0.f, 0.f, 0.f};

    for (int it = 0; it < 144; ++it) {
        const int kg = ksOff + it * 32;          // 32-chunk never crosses p
        const int p = kg >> 10;
        const int cb = kg & 1023;
        const int di = p / 3, dj = p - di * 3;

        __syncthreads();                          // all waves done reading previous tile
#pragma unroll
        for (int j = 0; j < 2; ++j) {
            int ii = siA[j] + di - 1, jj = sjA[j] + dj - 1;
            bool ok = ((unsigned)ii < 16u) && ((unsigned)jj < 16u);
            size_t aoff = ok ? ((((size_t)bA[j] << 8) + (size_t)(ii * 16 + jj)) << 10) + cb + qA[j] * 8
                             : 0;
            const u16* gah = ok ? CH + aoff : ZS;
            const u16* gal = ok ? CL + aoff : ZS;
            int lb = wave * 1024 + j * 512;       // u16 units, wave-uniform
            gl_lds16(gah, &Ah[lb]);
            gl_lds16(gal, &Al[lb]);
        }
        gl_lds16(srcBh + kg, &Bh[wave * 512]);
        gl_lds16(srcBl + kg, &Bl[wave * 512]);
        __syncthreads();

        f16x8 fah[4], fal[4], fbh[2], fbl[2];
#pragma unroll
        for (int x = 0; x < 4; ++x) {
            fah[x] = *(const f16x8*)&Ah[offA[x]];
            fal[x] = *(const f16x8*)&Al[offA[x]];
        }
#pragma unroll
        for (int x = 0; x < 2; ++x) {
            fbh[x] = *(const f16x8*)&Bh[offB[x]];
            fbl[x] = *(const f16x8*)&Bl[offB[x]];
        }
#pragma unroll
        for (int tm = 0; tm < 4; ++tm)
#pragma unroll
            for (int tn = 0; tn < 2; ++tn) {
                acc[tm][tn] = __builtin_amdgcn_mfma_f32_16x16x32_f16(fal[tm], fbh[tn], acc[tm][tn], 0, 0, 0);
                acc[tm][tn] = __builtin_amdgcn_mfma_f32_16x16x32_f16(fah[tm], fbl[tn], acc[tm][tn], 0, 0, 0);
                acc[tm][tn] = __builtin_amdgcn_mfma_f32_16x16x32_f16(fah[tm], fbh[tn], acc[tm][tn], 0, 0, 0);
            }
    }

    // epilogue: C/D layout col=lane&15, row=quad*4+reg
#pragma unroll
    for (int tm = 0; tm < 4; ++tm) {
        int mbase = mb * 128 + wm * 64 + tm * 16 + quad * 4;
#pragma unroll
        for (int tn = 0; tn < 2; ++tn) {
            int o = nb * 64 + wn * 32 + tn * 16 + l16;
#pragma unroll
            for (int r = 0; r < 4; ++r)
                XP[(size_t)(mbase + r) * COUT + o] = acc[tm][tn][r];
        }
    }
}

// ---------------- heads (unchanged math) ----------------
__global__ __launch_bounds__(64)
void heads_kernel(const float* __restrict__ XP0, const float* __restrict__ XP1,
                  const float* __restrict__ conv_b, const float* __restrict__ HW,
                  const float* __restrict__ cls_b, const float* __restrict__ reg_b,
                  float* __restrict__ scores, float* __restrict__ regs) {
    __shared__ float xs[512];
    int mm = blockIdx.x;
    int t = threadIdx.x;
#pragma unroll
    for (int q = 0; q < 8; ++q) {
        int c = t + 64 * q;
        xs[c] = fmaxf(XP0[(size_t)mm * COUT + c] + XP1[(size_t)mm * COUT + c] + conv_b[c], 0.f);
    }
    __syncthreads();
    if (t < 45) {
        float acc = (t < 9) ? cls_b[t] : reg_b[t - 9];
        for (int c = 0; c < 512; ++c) acc = fmaf(xs[c], HW[c * 45 + t], acc);
        int b = mm >> 8, cell = mm & 255;
        if (t < 9) {
            scores[(size_t)b * 2304 + cell * 9 + t] = 1.f / (1.f + expf(-acc));
        } else {
            int ch = t - 9;
            regs[((size_t)b * 2304 + cell * 9 + (ch >> 2)) * 4 + (ch & 3)] = acc;
        }
    }
}

// ---------------- top-k + decode + NMS per image (unchanged) ----------------
__global__ __launch_bounds__(256)
void topk_nms(const float* __restrict__ scores, const float* __restrict__ regs,
              float* __restrict__ rois, float* __restrict__ valid) {
    __shared__ float sc[2304];
    __shared__ float wv[4];
    __shared__ int   wi[4];
    __shared__ int   sel[TOPK];
    __shared__ float bx[TOPK][4];
    __shared__ float iou[TOPK * TOPK];
    __shared__ float keepsh[TOPK];
    int b = blockIdx.x, t = threadIdx.x;
    for (int q = t; q < 2304; q += 256) sc[q] = scores[(size_t)b * 2304 + q];
    __syncthreads();

    for (int k = 0; k < TOPK; ++k) {
        float bv = -1e30f; int bi = 1 << 30;
#pragma unroll
        for (int q = 0; q < 9; ++q) {
            int idx = t * 9 + q;
            float v = sc[idx];
            if (v > bv || (v == bv && idx < bi)) { bv = v; bi = idx; }
        }
        for (int off = 32; off; off >>= 1) {
            float ov = __shfl_down(bv, off);
            int   oi = __shfl_down(bi, off);
            if (ov > bv || (ov == bv && oi < bi)) { bv = ov; bi = oi; }
        }
        int lane = t & 63, w = t >> 6;
        if (lane == 0) { wv[w] = bv; wi[w] = bi; }
        __syncthreads();
        if (t == 0) {
            float fv = wv[0]; int fi = wi[0];
            for (int q = 1; q < 4; ++q)
                if (wv[q] > fv || (wv[q] == fv && wi[q] < fi)) { fv = wv[q]; fi = wi[q]; }
            sel[k] = fi;
            sc[fi] = -1e38f;
        }
        __syncthreads();
    }

    if (t < TOPK) {
        int n = sel[t];
        int cell = n / 9, a = n % 9;
        int ci = cell >> 4, cj = cell & 15;
        int siid = a / 3, riid = a % 3;
        const double scl[3] = {8.0, 16.0, 32.0};
        const double rat[3] = {0.5, 1.0, 2.0};
        double s = scl[siid], r = rat[riid];
        double wD = s * sqrt(r), hD = s / sqrt(r);
        double xc = (cj + 0.5) * 16.0, yc = (ci + 0.5) * 16.0;
        float ax1 = (float)(xc - wD / 2), ay1 = (float)(yc - hD / 2);
        float ax2 = (float)(xc + wD / 2), ay2 = (float)(yc + hD / 2);
        float aw = ax2 - ax1, ah = ay2 - ay1;
        float ctrx = ax1 + 0.5f * aw, ctry = ay1 + 0.5f * ah;
        const float* rg = regs + ((size_t)b * 2304 + n) * 4;
        float cx = rg[0] * aw + ctrx;
        float cy = rg[1] * ah + ctry;
        float pw = expf(rg[2]) * aw;
        float ph = expf(rg[3]) * ah;
        float x1 = cx - 0.5f * pw, y1 = cy - 0.5f * ph;
        float x2 = cx + 0.5f * pw, y2 = cy + 0.5f * ph;
        x1 = fminf(fmaxf(x1, 0.f), 256.f);
        y1 = fminf(fmaxf(y1, 0.f), 256.f);
        x2 = fminf(fmaxf(x2, 0.f), 256.f);
        y2 = fminf(fmaxf(y2, 0.f), 256.f);
        if (x2 - x1 < 1.f) x2 = x1 + 1.f;
        if (y2 - y1 < 1.f) y2 = y1 + 1.f;
        bx[t][0] = x1; bx[t][1] = y1; bx[t][2] = x2; bx[t][3] = y2;
    }
    __syncthreads();
    if (t < TOPK * TOPK) {
        int ii = t / TOPK, jj = t % TOPK;
        float xi1 = bx[ii][0], yi1 = bx[ii][1], xi2 = bx[ii][2], yi2 = bx[ii][3];
        float xj1 = bx[jj][0], yj1 = bx[jj][1], xj2 = bx[jj][2], yj2 = bx[jj][3];
        float ai = (xi2 - xi1) * (yi2 - yi1), aj = (xj2 - xj1) * (yj2 - yj1);
        float iw = fmaxf(fminf(xi2, xj2) - fmaxf(xi1, xj1), 0.f);
        float ih = fmaxf(fminf(yi2, yj2) - fmaxf(yi1, yj1), 0.f);
        float inter = iw * ih;
        iou[t] = inter / (ai + aj - inter);
    }
    __syncthreads();
    if (t == 0) {
        bool keep[TOPK];
        for (int q = 0; q < TOPK; ++q) keep[q] = true;
        for (int iK = 0; iK < TOPK; ++iK) {
            if (!keep[iK]) continue;
            for (int jK = iK + 1; jK < TOPK; ++jK)
                if (keep[jK] && iou[iK * TOPK + jK] > 0.85f) keep[jK] = false;
        }
        for (int q = 0; q < TOPK; ++q) keepsh[q] = keep[q] ? 1.f : 0.f;
    }
    __syncthreads();
    if (t < TOPK) {
        int rr = b * TOPK + t;
        rois[rr * 4 + 0] = bx[t][0]; rois[rr * 4 + 1] = bx[t][1];
        rois[rr * 4 + 2] = bx[t][2]; rois[rr * 4 + 3] = bx[t][3];
        valid[rr] = keepsh[t];
    }
}

// ---------------- roi labels (unchanged) ----------------
__global__ __launch_bounds__(256)
void roi_labels_k(const float* __restrict__ gt, const float* __restrict__ rois,
                  float* __restrict__ labels) {
    __shared__ float red[4];
    int r = blockIdx.x, t = threadIdx.x;
    int b = r / TOPK;
    int x1 = min(max((int)rois[r * 4 + 0], 0), 256);
    int y1 = min(max((int)rois[r * 4 + 1], 0), 256);
    int x2 = min(max((int)rois[r * 4 + 2], 0), 256);
    int y2 = min(max((int)rois[r * 4 + 3], 0), 256);
    int wdt = x2 - x1, hgt = y2 - y1;
    int cnt = wdt * hgt;
    float s = 0.f;
    if (cnt > 0) {
        const float* g = gt + (size_t)b * (IMG * IMG);
        for (int idx = t; idx < cnt; idx += 256) {
            int yy = y1 + idx / wdt, xx = x1 + idx % wdt;
            s += g[yy * IMG + xx];
        }
    }
    for (int off = 32; off; off >>= 1) s += __shfl_down(s, off);
    if ((t & 63) == 0) red[t >> 6] = s;
    __syncthreads();
    if (t == 0) {
        float tot = red[0] + red[1] + red[2] + red[3];
        labels[r] = (cnt > 0 && 2.f * tot > (float)cnt) ? 1.f : 0.f;
    }
}

// ---------------- fused per-ROI chain: align -> fc1(relu) -> fc2 -> normalize ----------------
// 4 rois per block; each phase replicates the previous kernels' per-element
// op order exactly (bit-identical results, intermediates in LDS).
__global__ __launch_bounds__(256)
void roi_fused(const float* __restrict__ clip, const float* __restrict__ rois,
               const float* __restrict__ w1, const float* __restrict__ b1,
               const float* __restrict__ w2, const float* __restrict__ b2,
               float* __restrict__ nfout) {
    __shared__ float pooled[4][1024];
    __shared__ float hsh[4][256];
    __shared__ float prsh[4][256];
    __shared__ float red[4];
    int t = threadIdx.x;
    int r0 = blockIdx.x * 4;

    // Phase A: roi-align, thread t covers channels t+256q
#pragma unroll
    for (int q4 = 0; q4 < 4; ++q4) {
        int r = r0 + q4;
        int b = r / TOPK;
        float rx1 = rois[r * 4 + 0] * 0.0625f, ry1 = rois[r * 4 + 1] * 0.0625f;
        float rw = fmaxf(rois[r * 4 + 2] * 0.0625f - rx1, 1.f);
        float rh = fmaxf(rois[r * 4 + 3] * 0.0625f - ry1, 1.f);
        float sx = rw / (float)POOLN, sy = rh / (float)POOLN;
        float acc[4] = {0.f, 0.f, 0.f, 0.f};
        for (int py = 0; py < POOLN; ++py) {
            float Y = ry1 + ((float)py + 0.5f) * sy;
            for (int px = 0; px < POOLN; ++px) {
                float Xx = rx1 + ((float)px + 0.5f) * sx;
                bool ok = (Y > -1.f) && (Y < 16.f) && (Xx > -1.f) && (Xx < 16.f);
                if (!ok) continue;
                float Xc = fminf(fmaxf(Xx, 0.f), 15.f);
                float Yc = fminf(fmaxf(Y, 0.f), 15.f);
                int x0 = (int)floorf(Xc), y0 = (int)floorf(Yc);
                int x1i = min(x0 + 1, 15), y1i = min(y0 + 1, 15);
                float lx = Xc - (float)x0, ly = Yc - (float)y0;
                float hx = 1.f - lx, hy = 1.f - ly;
                float w00 = hy * hx, w01 = hy * lx, w10 = ly * hx, w11 = ly * lx;
                const float* f00 = clip + (size_t)(1 + y0 * 16 + x0) * 32768 + (size_t)b * 1024;
                const float* f01 = clip + (size_t)(1 + y0 * 16 + x1i) * 32768 + (size_t)b * 1024;
                const float* f10 = clip + (size_t)(1 + y1i * 16 + x0) * 32768 + (size_t)b * 1024;
                const float* f11 = clip + (size_t)(1 + y1i * 16 + x1i) * 32768 + (size_t)b * 1024;
#pragma unroll
                for (int q = 0; q < 4; ++q) {
                    int c = t + 256 * q;
                    acc[q] += w00 * f00[c] + w01 * f01[c] + w10 * f10[c] + w11 * f11[c];
                }
            }
        }
#pragma unroll
        for (int q = 0; q < 4; ++q)
            pooled[q4][t + 256 * q] = acc[q] / 49.f;
    }
    __syncthreads();

    // Phase B: fc1024 + relu (same serial-c order as fc_kernel)
    {
        float bv = b1[t];
        float acc[4] = {bv, bv, bv, bv};
        for (int c = 0; c < 1024; ++c) {
            float wv = w1[(size_t)t * 1024 + c];
#pragma unroll
            for (int q = 0; q < 4; ++q) acc[q] = fmaf(pooled[q][c], wv, acc[q]);
        }
#pragma unroll
        for (int q = 0; q < 4; ++q) hsh[q][t] = fmaxf(acc[q], 0.f);
    }
    __syncthreads();

    // Phase C: fc256 (no relu)
    {
        float bv = b2[t];
        float acc[4] = {bv, bv, bv, bv};
        for (int c = 0; c < 256; ++c) {
            float wv = w2[(size_t)t * 256 + c];
#pragma unroll
            for (int q = 0; q < 4; ++q) acc[q] = fmaf(hsh[q][c], wv, acc[q]);
        }
#pragma unroll
        for (int q = 0; q < 4; ++q) prsh[q][t] = acc[q];
    }
    __syncthreads();

    // Phase D: normalize rows (same reduction tree as normalize_rows)
    for (int q = 0; q < 4; ++q) {
        float v = prsh[q][t];
        float ss = v * v;
        for (int off = 32; off; off >>= 1) ss += __shfl_down(ss, off);
        if ((t & 63) == 0) red[t >> 6] = ss;
        __syncthreads();
        float tot = red[0] + red[1] + red[2] + red[3];
        float denom = fmaxf(sqrtf(tot), 1e-12f);
        nfout[(size_t)(r0 + q) * 256 + t] = v / denom;
        __syncthreads();
    }
}

// ---------------- supcon, 4 i-rows per block (bit-identical per-(i,j) math) ----------------
__global__ __launch_bounds__(256)
void supcon_rows4(const float* __restrict__ nf, const float* __restrict__ labels,
                  const float* __restrict__ valid, float* __restrict__ rowl,
                  float* __restrict__ rowa) {
    __shared__ float my[4][256];
    __shared__ float labs[NROI], vals[NROI];
    __shared__ float wsa[4][4], wsp[4][4];
    __shared__ int wnp[4][4];
    int i0 = blockIdx.x * 4, t = threadIdx.x;
#pragma unroll
    for (int iq = 0; iq < 4; ++iq) my[iq][t] = nf[(size_t)(i0 + iq) * 256 + t];
    for (int q = t; q < NROI; q += 256) { labs[q] = labels[q]; vals[q] = valid[q]; }
    __syncthreads();
    int w = t >> 6, lane = t & 63;
    float4 my4[4];
    float vi[4], li[4];
#pragma unroll
    for (int iq = 0; iq < 4; ++iq) {
        my4[iq] = ((const float4*)my[iq])[lane];
        vi[iq] = vals[i0 + iq];
        li[iq] = labs[i0 + iq];
    }
    float sa[4] = {0.f, 0.f, 0.f, 0.f}, sp[4] = {0.f, 0.f, 0.f, 0.f};
    int np[4] = {0, 0, 0, 0};
    for (int j = w; j < NROI; j += 4) {
        float4 v4 = ((const float4*)(nf + (size_t)j * 256))[lane];
        float vj = vals[j], lj = labs[j];
#pragma unroll
        for (int iq = 0; iq < 4; ++iq) {
            float p = my4[iq].x * v4.x;
            p = fmaf(my4[iq].y, v4.y, p);
            p = fmaf(my4[iq].z, v4.z, p);
            p = fmaf(my4[iq].w, v4.w, p);
#pragma unroll
            for (int off = 32; off; off >>= 1) p += __shfl_xor(p, off);
            if (vi[iq] > 0.5f && j != i0 + iq && vj > 0.5f) {
                float e = expf(p / 0.07f);
                sa[iq] += e;
                if (lj == li[iq]) { sp[iq] += e; np[iq]++; }
            }
        }
    }
    if (lane == 0) {
#pragma unroll
        for (int iq = 0; iq < 4; ++iq) { wsa[iq][w] = sa[iq]; wsp[iq][w] = sp[iq]; wnp[iq][w] = np[iq]; }
    }
    __syncthreads();
    if (t == 0) {
#pragma unroll
        for (int iq = 0; iq < 4; ++iq) {
            float s_a = wsa[iq][0] + wsa[iq][1] + wsa[iq][2] + wsa[iq][3];
            float s_p = wsp[iq][0] + wsp[iq][1] + wsp[iq][2] + wsp[iq][3];
            int tnp = wnp[iq][0] + wnp[iq][1] + wnp[iq][2] + wnp[iq][3];
            bool active = (vi[iq] > 0.5f) && (tnp > 0);
            float ratio = s_p / (s_a + 1e-12f);
            float l = -logf(ratio + 1e-12f);
            rowl[i0 + iq] = active ? l : 0.f;
            rowa[i0 + iq] = active ? 1.f : 0.f;
        }
    }
}

// ---------------- final scalar reduce (unchanged) ----------------
__global__ __launch_bounds__(256)
void final_reduce(const float* __restrict__ rowl, const float* __restrict__ rowa,
                  float* __restrict__ out) {
    __shared__ float rl[4], ra[4];
    int t = threadIdx.x;
    float sl = 0.f, sa = 0.f;
    for (int q = t; q < NROI; q += 256) { sl += rowl[q]; sa += rowa[q]; }
    for (int off = 32; off; off >>= 1) { sl += __shfl_down(sl, off); sa += __shfl_down(sa, off); }
    if ((t & 63) == 0) { rl[t >> 6] = sl; ra[t >> 6] = sa; }
    __syncthreads();
    if (t == 0) {
        float L = rl[0] + rl[1] + rl[2] + rl[3];
        float A = ra[0] + ra[1] + ra[2] + ra[3];
        out[0] = (A > 0.f) ? (L / fmaxf(A, 1.f)) : 0.f;
    }
}

// ---------------- launch ----------------
extern "C" void kernel_launch(void* const* d_in, const int* in_sizes, int n_in,
                              void* d_out, int out_size, void* d_ws, size_t ws_size,
                              hipStream_t stream) {
    const float* clip   = (const float*)d_in[0];
    const float* gt     = (const float*)d_in[1];
    const float* conv_w = (const float*)d_in[2];
    const float* conv_b = (const float*)d_in[3];
    const float* cls_w  = (const float*)d_in[4];
    const float* cls_b  = (const float*)d_in[5];
    const float* reg_w  = (const float*)d_in[6];
    const float* reg_b  = (const float*)d_in[7];
    const float* w1     = (const float*)d_in[8];
    const float* b1     = (const float*)d_in[9];
    const float* w2     = (const float*)d_in[10];
    const float* b2     = (const float*)d_in[11];

    if (ws_size < WS_FLOATS * sizeof(float)) return;  // visible failure if ws too small

    float* ws  = (float*)d_ws;
    float* XP0 = ws + O_XP0;
    float* XP1 = ws + O_XP1;
    u16*   CH  = (u16*)(ws + O_CH);
    u16*   CL  = (u16*)(ws + O_CL);
    u16*   WHp = (u16*)(ws + O_WH);
    u16*   WLp = (u16*)(ws + O_WL);
    u16*   ZS  = (u16*)(ws + O_Z);
    float* HW  = ws + O_HW;
    float* SC  = ws + O_SC;
    float* RG  = ws + O_RG;
    float* ROI = ws + O_ROI;
    float* VAL = ws + O_VAL;
    float* LAB = ws + O_LAB;
    float* NF  = ws + O_NF;
    float* RL  = ws + O_RL;
    float* RA  = ws + O_RA;

    convert_all<<<NB_CLIP + NB_W + NB_Z + NB_HW, 256, 0, stream>>>(
        clip, conv_w, cls_w, reg_w, CH, CL, WHp, WLp, ZS, HW);
    conv_mfma<<<1024, 256, 0, stream>>>(CH, CL, WHp, WLp, ZS, XP0, XP1);
    heads_kernel<<<NPOS, 64, 0, stream>>>(XP0, XP1, conv_b, HW, cls_b, reg_b, SC, RG);
    topk_nms<<<BATCH, 256, 0, stream>>>(SC, RG, ROI, VAL);
    roi_labels_k<<<NROI, 256, 0, stream>>>(gt, ROI, LAB);
    roi_fused<<<NROI / 4, 256, 0, stream>>>(clip, ROI, w1, b1, w2, b2, NF);
    supcon_rows4<<<NROI / 4, 256, 0, stream>>>(NF, LAB, VAL, RL, RA);
    final_reduce<<<1, 256, 0, stream>>>(RL, RA, (float*)d_out);
}

// Round 6
// 708.198 us; speedup vs baseline: 1.4753x; 1.4753x over previous
//
#include <hip/hip_runtime.h>
#include <hip/hip_bf16.h>
#include <math.h>

typedef unsigned short u16;
typedef unsigned int u32;
typedef _Float16 f16;
typedef _Float16 f16x8 __attribute__((ext_vector_type(8)));
typedef float f32x4 __attribute__((ext_vector_type(4)));

// ---------------- constants ----------------
#define BATCH 32
#define CIN   1024
#define COUT  512
#define NPOS  8192
#define K9    9216
#define KHALF 4608
#define TOPK  30
#define NROI  960
#define POOLN 7
#define IMG   256

// ---------------- ws layout (float units) ----------------
#define O_XP0  0ull
#define O_XP1  4194304ull
#define O_CH   8388608ull      // u16[8388608]
#define O_CL   12582912ull
#define O_WH   16777216ull     // u16[4718592]
#define O_WL   19136512ull
#define O_Z    21495808ull     // 512 u16 zeros
#define O_HW   21496064ull
#define O_SC   21519104ull
#define O_RG   21592832ull
#define O_ROI  21887744ull
#define O_VAL  21891584ull
#define O_LAB  21892544ull
#define WS_FLOATS 21893504ull
// overlays on XP0/XP1 region (used only after heads consumed XP0/XP1):
#define O_PO   0ull
#define O_H    983040ull
#define O_PR   1228800ull
#define O_NF   1474560ull
#define O_RL   1720320ull
#define O_RA   1721280ull

// async global->LDS, 16 bytes/lane, LDS dest = wave-uniform base + lane*16
__device__ __forceinline__ void gl_lds16(const void* g, void* l) {
    __builtin_amdgcn_global_load_lds(
        (const __attribute__((address_space(1))) u32*)g,
        (__attribute__((address_space(3))) u32*)l,
        16, 0, 0);
}

// ---------------- fp16 hi/lo split ----------------
__device__ inline void split16(float x, u16& h, u16& l) {
    f16 hv = (f16)x;
    f16 lv = (f16)(x - (float)hv);
    h = *(u16*)&hv;
    l = *(u16*)&lv;
}

// ---------------- fused prep: clip convert + w convert + zeros + hw repack ----------------
#define NB_CLIP 8192
#define NB_W    18432
#define NB_Z    1
#define NB_HW   90
__global__ __launch_bounds__(256)
void convert_all(const float* __restrict__ clip, const float* __restrict__ conv_w,
                 const float* __restrict__ cls_w, const float* __restrict__ reg_w,
                 u16* __restrict__ CH, u16* __restrict__ CL,
                 u16* __restrict__ WH, u16* __restrict__ WL,
                 u16* __restrict__ Z, float* __restrict__ HW) {
    int bid = blockIdx.x, t = threadIdx.x;
    if (bid < NB_CLIP) {
        int tid = bid * 256 + t;
        int c4  = (tid & 255) * 4;
        int pos = (tid >> 8) & 255;
        int b   = tid >> 16;
        float4 v = *(const float4*)(clip + ((size_t)(1 + pos) * 32 + b) * 1024 + c4);
        float xs[4] = {v.x, v.y, v.z, v.w};
        ushort4 hh, ll;
        u16* hp = (u16*)&hh; u16* lp = (u16*)&ll;
#pragma unroll
        for (int q = 0; q < 4; ++q) split16(xs[q], hp[q], lp[q]);
        size_t o = ((size_t)(b * 256 + pos)) * 1024 + c4;
        *(ushort4*)(CH + o) = hh;
        *(ushort4*)(CL + o) = ll;
    } else if (bid < NB_CLIP + NB_W) {
        int bid2 = bid - NB_CLIP;
        int k = (bid2 % 36) * 256 + t;
        int o = bid2 / 36;
        int c = k & 1023, p = k >> 10;
        float x = conv_w[(size_t)o * K9 + c * 9 + p];
        u16 h, l;
        split16(x, h, l);
        WH[(size_t)o * K9 + k] = h;
        WL[(size_t)o * K9 + k] = l;
    } else if (bid < NB_CLIP + NB_W + NB_Z) {
        Z[t] = 0; Z[256 + t] = 0;
    } else {
        int tid2 = (bid - NB_CLIP - NB_W - NB_Z) * 256 + t;
        if (tid2 < 45 * 512) {
            int c = tid2 / 45, a = tid2 % 45;
            HW[tid2] = (a < 9) ? cls_w[a * 512 + c] : reg_w[(a - 9) * 512 + c];
        }
    }
}

// ---------------- MFMA conv GEMM (fp16x2 split, 3 MFMA/product) ----------------
// Round-4 tile restored: TM=128, TN=128, BK=32, grid 512 (2 blocks/CU, 32 KB LDS).
// NEW gid decode: gid = nb*128 + (mb*2 + ks)  ->  gid%8 = (mb*2+ks)%8.
// With round-robin XCD dispatch, the 4 nb-sharers of each A tile land on the
// SAME XCD (A fetched once into its L2), each XCD has a fixed ks, and its 16
// resident mb-groups share the same 4 B slices (streamed, L2-window hits).
// Per-output accumulation order is bit-identical to round 4.
__global__ __launch_bounds__(256, 2)
void conv_mfma(const u16* __restrict__ CH, const u16* __restrict__ CL,
               const u16* __restrict__ WH, const u16* __restrict__ WL,
               const u16* __restrict__ ZS,
               float* __restrict__ XP0, float* __restrict__ XP1) {
    __shared__ __align__(16) u16 Ah[4096];   // 128 rows x 32 k; slot s of row r holds granule s^((r>>1)&3)
    __shared__ __align__(16) u16 Al[4096];
    __shared__ __align__(16) u16 Bh[4096];
    __shared__ __align__(16) u16 Bl[4096];

    const int t = threadIdx.x;
    const int gid = blockIdx.x;
    const int nb = gid >> 7;            // 0..3
    const int g  = gid & 127;
    const int mb = g >> 1;              // 0..63
    const int ks = g & 1;
    const int ksOff = ks * KHALF;
    float* __restrict__ XP = ks ? XP1 : XP0;

    const int wave = t >> 6, lane = t & 63;

    // staging roles: call j (0/1): lane covers row r = wave*32 + j*16 + lane/4,
    // physical slot s = lane&3, data granule q = s ^ ((r>>1)&3)
    int qA[2], siA[2], sjA[2], bA[2];
    const u16* srcBh[2];
    const u16* srcBl[2];
#pragma unroll
    for (int j = 0; j < 2; ++j) {
        int r = wave * 32 + j * 16 + (lane >> 2);
        int s = lane & 3;
        int q = s ^ ((r >> 1) & 3);
        qA[j] = q;
        int m = mb * 128 + r;
        bA[j] = m >> 8;
        int ij = m & 255;
        siA[j] = ij >> 4; sjA[j] = ij & 15;
        int o = nb * 128 + r;
        srcBh[j] = WH + (size_t)o * K9 + q * 8;
        srcBl[j] = WL + (size_t)o * K9 + q * 8;
    }

    // compute ids
    const int wm = wave >> 1, wn = wave & 1;
    const int l16 = lane & 15, quad = lane >> 4;
    int offA[4], offB[4];                       // u16 indices into LDS
#pragma unroll
    for (int q = 0; q < 4; ++q) {
        int ar = wm * 64 + q * 16 + l16;
        offA[q] = ar * 32 + ((quad ^ ((ar >> 1) & 3)) << 3);
        int br = wn * 64 + q * 16 + l16;
        offB[q] = br * 32 + ((quad ^ ((br >> 1) & 3)) << 3);
    }

    f32x4 acc[4][4];
#pragma unroll
    for (int r = 0; r < 4; ++r)
#pragma unroll
        for (int c = 0; c < 4; ++c) acc[r][c] = (f32x4){0.f, 0.f, 0.f, 0.f};

    for (int it = 0; it < 144; ++it) {
        const int kg = ksOff + it * 32;          // 32-chunk never crosses p
        const int p = kg >> 10;
        const int cb = kg & 1023;
        const int di = p / 3, dj = p - di * 3;

        __syncthreads();                          // all waves done reading previous tile
#pragma unroll
        for (int j = 0; j < 2; ++j) {
            int ii = siA[j] + di - 1, jj = sjA[j] + dj - 1;
            bool ok = ((unsigned)ii < 16u) && ((unsigned)jj < 16u);
            size_t aoff = ok ? ((((size_t)bA[j] << 8) + (size_t)(ii * 16 + jj)) << 10) + cb + qA[j] * 8
                             : 0;
            const u16* gah = ok ? CH + aoff : ZS;
            const u16* gal = ok ? CL + aoff : ZS;
            int lb = wave * 1024 + j * 512;       // u16 units, wave-uniform
            gl_lds16(gah,           &Ah[lb]);
            gl_lds16(gal,           &Al[lb]);
            gl_lds16(srcBh[j] + kg, &Bh[lb]);
            gl_lds16(srcBl[j] + kg, &Bl[lb]);
        }
        __syncthreads();

        f16x8 fah[4], fal[4], fbh[4], fbl[4];
#pragma unroll
        for (int x = 0; x < 4; ++x) {
            fah[x] = *(const f16x8*)&Ah[offA[x]];
            fal[x] = *(const f16x8*)&Al[offA[x]];
            fbh[x] = *(const f16x8*)&Bh[offB[x]];
            fbl[x] = *(const f16x8*)&Bl[offB[x]];
        }
#pragma unroll
        for (int tm = 0; tm < 4; ++tm)
#pragma unroll
            for (int tn = 0; tn < 4; ++tn) {
                acc[tm][tn] = __builtin_amdgcn_mfma_f32_16x16x32_f16(fal[tm], fbh[tn], acc[tm][tn], 0, 0, 0);
                acc[tm][tn] = __builtin_amdgcn_mfma_f32_16x16x32_f16(fah[tm], fbl[tn], acc[tm][tn], 0, 0, 0);
                acc[tm][tn] = __builtin_amdgcn_mfma_f32_16x16x32_f16(fah[tm], fbh[tn], acc[tm][tn], 0, 0, 0);
            }
    }

    // epilogue: C/D layout col=lane&15, row=quad*4+reg
#pragma unroll
    for (int tm = 0; tm < 4; ++tm) {
        int mbase = mb * 128 + wm * 64 + tm * 16 + quad * 4;
#pragma unroll
        for (int tn = 0; tn < 4; ++tn) {
            int o = nb * 128 + wn * 64 + tn * 16 + l16;
#pragma unroll
            for (int r = 0; r < 4; ++r)
                XP[(size_t)(mbase + r) * COUT + o] = acc[tm][tn][r];
        }
    }
}

// ---------------- heads (unchanged math) ----------------
__global__ __launch_bounds__(64)
void heads_kernel(const float* __restrict__ XP0, const float* __restrict__ XP1,
                  const float* __restrict__ conv_b, const float* __restrict__ HW,
                  const float* __restrict__ cls_b, const float* __restrict__ reg_b,
                  float* __restrict__ scores, float* __restrict__ regs) {
    __shared__ float xs[512];
    int mm = blockIdx.x;
    int t = threadIdx.x;
#pragma unroll
    for (int q = 0; q < 8; ++q) {
        int c = t + 64 * q;
        xs[c] = fmaxf(XP0[(size_t)mm * COUT + c] + XP1[(size_t)mm * COUT + c] + conv_b[c], 0.f);
    }
    __syncthreads();
    if (t < 45) {
        float acc = (t < 9) ? cls_b[t] : reg_b[t - 9];
        for (int c = 0; c < 512; ++c) acc = fmaf(xs[c], HW[c * 45 + t], acc);
        int b = mm >> 8, cell = mm & 255;
        if (t < 9) {
            scores[(size_t)b * 2304 + cell * 9 + t] = 1.f / (1.f + expf(-acc));
        } else {
            int ch = t - 9;
            regs[((size_t)b * 2304 + cell * 9 + (ch >> 2)) * 4 + (ch & 3)] = acc;
        }
    }
}

// ---------------- top-k + decode + NMS per image (unchanged) ----------------
__global__ __launch_bounds__(256)
void topk_nms(const float* __restrict__ scores, const float* __restrict__ regs,
              float* __restrict__ rois, float* __restrict__ valid) {
    __shared__ float sc[2304];
    __shared__ float wv[4];
    __shared__ int   wi[4];
    __shared__ int   sel[TOPK];
    __shared__ float bx[TOPK][4];
    __shared__ float iou[TOPK * TOPK];
    __shared__ float keepsh[TOPK];
    int b = blockIdx.x, t = threadIdx.x;
    for (int q = t; q < 2304; q += 256) sc[q] = scores[(size_t)b * 2304 + q];
    __syncthreads();

    for (int k = 0; k < TOPK; ++k) {
        float bv = -1e30f; int bi = 1 << 30;
#pragma unroll
        for (int q = 0; q < 9; ++q) {
            int idx = t * 9 + q;
            float v = sc[idx];
            if (v > bv || (v == bv && idx < bi)) { bv = v; bi = idx; }
        }
        for (int off = 32; off; off >>= 1) {
            float ov = __shfl_down(bv, off);
            int   oi = __shfl_down(bi, off);
            if (ov > bv || (ov == bv && oi < bi)) { bv = ov; bi = oi; }
        }
        int lane = t & 63, w = t >> 6;
        if (lane == 0) { wv[w] = bv; wi[w] = bi; }
        __syncthreads();
        if (t == 0) {
            float fv = wv[0]; int fi = wi[0];
            for (int q = 1; q < 4; ++q)
                if (wv[q] > fv || (wv[q] == fv && wi[q] < fi)) { fv = wv[q]; fi = wi[q]; }
            sel[k] = fi;
            sc[fi] = -1e38f;
        }
        __syncthreads();
    }

    if (t < TOPK) {
        int n = sel[t];
        int cell = n / 9, a = n % 9;
        int ci = cell >> 4, cj = cell & 15;
        int siid = a / 3, riid = a % 3;
        const double scl[3] = {8.0, 16.0, 32.0};
        const double rat[3] = {0.5, 1.0, 2.0};
        double s = scl[siid], r = rat[riid];
        double wD = s * sqrt(r), hD = s / sqrt(r);
        double xc = (cj + 0.5) * 16.0, yc = (ci + 0.5) * 16.0;
        float ax1 = (float)(xc - wD / 2), ay1 = (float)(yc - hD / 2);
        float ax2 = (float)(xc + wD / 2), ay2 = (float)(yc + hD / 2);
        float aw = ax2 - ax1, ah = ay2 - ay1;
        float ctrx = ax1 + 0.5f * aw, ctry = ay1 + 0.5f * ah;
        const float* rg = regs + ((size_t)b * 2304 + n) * 4;
        float cx = rg[0] * aw + ctrx;
        float cy = rg[1] * ah + ctry;
        float pw = expf(rg[2]) * aw;
        float ph = expf(rg[3]) * ah;
        float x1 = cx - 0.5f * pw, y1 = cy - 0.5f * ph;
        float x2 = cx + 0.5f * pw, y2 = cy + 0.5f * ph;
        x1 = fminf(fmaxf(x1, 0.f), 256.f);
        y1 = fminf(fmaxf(y1, 0.f), 256.f);
        x2 = fminf(fmaxf(x2, 0.f), 256.f);
        y2 = fminf(fmaxf(y2, 0.f), 256.f);
        if (x2 - x1 < 1.f) x2 = x1 + 1.f;
        if (y2 - y1 < 1.f) y2 = y1 + 1.f;
        bx[t][0] = x1; bx[t][1] = y1; bx[t][2] = x2; bx[t][3] = y2;
    }
    __syncthreads();
    if (t < TOPK * TOPK) {
        int ii = t / TOPK, jj = t % TOPK;
        float xi1 = bx[ii][0], yi1 = bx[ii][1], xi2 = bx[ii][2], yi2 = bx[ii][3];
        float xj1 = bx[jj][0], yj1 = bx[jj][1], xj2 = bx[jj][2], yj2 = bx[jj][3];
        float ai = (xi2 - xi1) * (yi2 - yi1), aj = (xj2 - xj1) * (yj2 - yj1);
        float iw = fmaxf(fminf(xi2, xj2) - fmaxf(xi1, xj1), 0.f);
        float ih = fmaxf(fminf(yi2, yj2) - fmaxf(yi1, yj1), 0.f);
        float inter = iw * ih;
        iou[t] = inter / (ai + aj - inter);
    }
    __syncthreads();
    if (t == 0) {
        bool keep[TOPK];
        for (int q = 0; q < TOPK; ++q) keep[q] = true;
        for (int iK = 0; iK < TOPK; ++iK) {
            if (!keep[iK]) continue;
            for (int jK = iK + 1; jK < TOPK; ++jK)
                if (keep[jK] && iou[iK * TOPK + jK] > 0.85f) keep[jK] = false;
        }
        for (int q = 0; q < TOPK; ++q) keepsh[q] = keep[q] ? 1.f : 0.f;
    }
    __syncthreads();
    if (t < TOPK) {
        int rr = b * TOPK + t;
        rois[rr * 4 + 0] = bx[t][0]; rois[rr * 4 + 1] = bx[t][1];
        rois[rr * 4 + 2] = bx[t][2]; rois[rr * 4 + 3] = bx[t][3];
        valid[rr] = keepsh[t];
    }
}

// ---------------- fused independent per-ROI kernels: align (bid<960) + labels ----------------
__global__ __launch_bounds__(256)
void align_labels(const float* __restrict__ clip, const float* __restrict__ gt,
                  const float* __restrict__ rois,
                  float* __restrict__ pooled, float* __restrict__ labels) {
    int bid = blockIdx.x, t = threadIdx.x;
    if (bid < NROI) {
        int r = bid;
        int b = r / TOPK;
        float rx1 = rois[r * 4 + 0] * 0.0625f, ry1 = rois[r * 4 + 1] * 0.0625f;
        float rw = fmaxf(rois[r * 4 + 2] * 0.0625f - rx1, 1.f);
        float rh = fmaxf(rois[r * 4 + 3] * 0.0625f - ry1, 1.f);
        float sx = rw / (float)POOLN, sy = rh / (float)POOLN;
        float acc[4] = {0.f, 0.f, 0.f, 0.f};
        for (int py = 0; py < POOLN; ++py) {
            float Y = ry1 + ((float)py + 0.5f) * sy;
            for (int px = 0; px < POOLN; ++px) {
                float Xx = rx1 + ((float)px + 0.5f) * sx;
                bool ok = (Y > -1.f) && (Y < 16.f) && (Xx > -1.f) && (Xx < 16.f);
                if (!ok) continue;
                float Xc = fminf(fmaxf(Xx, 0.f), 15.f);
                float Yc = fminf(fmaxf(Y, 0.f), 15.f);
                int x0 = (int)floorf(Xc), y0 = (int)floorf(Yc);
                int x1i = min(x0 + 1, 15), y1i = min(y0 + 1, 15);
                float lx = Xc - (float)x0, ly = Yc - (float)y0;
                float hx = 1.f - lx, hy = 1.f - ly;
                float w00 = hy * hx, w01 = hy * lx, w10 = ly * hx, w11 = ly * lx;
                const float* f00 = clip + (size_t)(1 + y0 * 16 + x0) * 32768 + (size_t)b * 1024;
                const float* f01 = clip + (size_t)(1 + y0 * 16 + x1i) * 32768 + (size_t)b * 1024;
                const float* f10 = clip + (size_t)(1 + y1i * 16 + x0) * 32768 + (size_t)b * 1024;
                const float* f11 = clip + (size_t)(1 + y1i * 16 + x1i) * 32768 + (size_t)b * 1024;
#pragma unroll
                for (int q = 0; q < 4; ++q) {
                    int c = t + 256 * q;
                    acc[q] += w00 * f00[c] + w01 * f01[c] + w10 * f10[c] + w11 * f11[c];
                }
            }
        }
#pragma unroll
        for (int q = 0; q < 4; ++q)
            pooled[(size_t)r * 1024 + t + 256 * q] = acc[q] / 49.f;
    } else {
        __shared__ float red[4];
        int r = bid - NROI;
        int b = r / TOPK;
        int x1 = min(max((int)rois[r * 4 + 0], 0), 256);
        int y1 = min(max((int)rois[r * 4 + 1], 0), 256);
        int x2 = min(max((int)rois[r * 4 + 2], 0), 256);
        int y2 = min(max((int)rois[r * 4 + 3], 0), 256);
        int wdt = x2 - x1, hgt = y2 - y1;
        int cnt = wdt * hgt;
        float s = 0.f;
        if (cnt > 0) {
            const float* g = gt + (size_t)b * (IMG * IMG);
            for (int idx = t; idx < cnt; idx += 256) {
                int yy = y1 + idx / wdt, xx = x1 + idx % wdt;
                s += g[yy * IMG + xx];
            }
        }
        for (int off = 32; off; off >>= 1) s += __shfl_down(s, off);
        if ((t & 63) == 0) red[t >> 6] = s;
        __syncthreads();
        if (t == 0) {
            float tot = red[0] + red[1] + red[2] + red[3];
            labels[r] = (cnt > 0 && 2.f * tot > (float)cnt) ? 1.f : 0.f;
        }
    }
}

// ---------------- generic FC (out dim 256), 4 rows per block ----------------
template <int IN>
__global__ __launch_bounds__(256)
void fc_kernel(const float* __restrict__ in, const float* __restrict__ w,
               const float* __restrict__ bias, float* __restrict__ out, int do_relu) {
    __shared__ float rows[4][IN];
    int r0 = blockIdx.x * 4, t = threadIdx.x;
    for (int q = 0; q < 4; ++q)
        for (int c = t; c < IN; c += 256)
            rows[q][c] = in[(size_t)(r0 + q) * IN + c];
    __syncthreads();
    float bv = bias[t];
    float acc[4] = {bv, bv, bv, bv};
    for (int c = 0; c < IN; ++c) {
        float wv = w[(size_t)t * IN + c];
#pragma unroll
        for (int q = 0; q < 4; ++q) acc[q] = fmaf(rows[q][c], wv, acc[q]);
    }
#pragma unroll
    for (int q = 0; q < 4; ++q) {
        float v = acc[q];
        if (do_relu) v = fmaxf(v, 0.f);
        out[(size_t)(r0 + q) * 256 + t] = v;
    }
}

// ---------------- row normalize ----------------
__global__ __launch_bounds__(256)
void normalize_rows(const float* __restrict__ proj, float* __restrict__ nf) {
    __shared__ float red[4];
    int r = blockIdx.x, t = threadIdx.x;
    float v = proj[(size_t)r * 256 + t];
    float ss = v * v;
    for (int off = 32; off; off >>= 1) ss += __shfl_down(ss, off);
    if ((t & 63) == 0) red[t >> 6] = ss;
    __syncthreads();
    float tot = red[0] + red[1] + red[2] + red[3];
    float denom = fmaxf(sqrtf(tot), 1e-12f);
    nf[(size_t)r * 256 + t] = v / denom;
}

// ---------------- supcon per-row (round-4 float4 version) ----------------
__global__ __launch_bounds__(256)
void supcon_rows(const float* __restrict__ nf, const float* __restrict__ labels,
                 const float* __restrict__ valid, float* __restrict__ rowl,
                 float* __restrict__ rowa) {
    __shared__ float my[256];
    __shared__ float labs[NROI], vals[NROI];
    __shared__ float wsa[4], wsp[4];
    __shared__ int wnp[4];
    int i = blockIdx.x, t = threadIdx.x;
    my[t] = nf[(size_t)i * 256 + t];
    for (int q = t; q < NROI; q += 256) { labs[q] = labels[q]; vals[q] = valid[q]; }
    __syncthreads();
    float vi = vals[i], li = labs[i];
    float sum_all = 0.f, sum_pos = 0.f;
    int np = 0;
    int w = t >> 6, lane = t & 63;
    float4 my4 = ((const float4*)my)[lane];
    if (vi > 0.5f) {
        for (int j = w; j < NROI; j += 4) {
            float4 v4 = ((const float4*)(nf + (size_t)j * 256))[lane];
            float p = my4.x * v4.x;
            p = fmaf(my4.y, v4.y, p);
            p = fmaf(my4.z, v4.z, p);
            p = fmaf(my4.w, v4.w, p);
#pragma unroll
            for (int off = 32; off; off >>= 1) p += __shfl_xor(p, off);
            if (j != i && vals[j] > 0.5f) {
                float e = expf(p / 0.07f);
                sum_all += e;
                if (labs[j] == li) { sum_pos += e; np++; }
            }
        }
    }
    if (lane == 0) { wsa[w] = sum_all; wsp[w] = sum_pos; wnp[w] = np; }
    __syncthreads();
    if (t == 0) {
        float sa = wsa[0] + wsa[1] + wsa[2] + wsa[3];
        float sp = wsp[0] + wsp[1] + wsp[2] + wsp[3];
        int tnp = wnp[0] + wnp[1] + wnp[2] + wnp[3];
        bool active = (vi > 0.5f) && (tnp > 0);
        float ratio = sp / (sa + 1e-12f);
        float l = -logf(ratio + 1e-12f);
        rowl[i] = active ? l : 0.f;
        rowa[i] = active ? 1.f : 0.f;
    }
}

// ---------------- final scalar reduce ----------------
__global__ __launch_bounds__(256)
void final_reduce(const float* __restrict__ rowl, const float* __restrict__ rowa,
                  float* __restrict__ out) {
    __shared__ float rl[4], ra[4];
    int t = threadIdx.x;
    float sl = 0.f, sa = 0.f;
    for (int q = t; q < NROI; q += 256) { sl += rowl[q]; sa += rowa[q]; }
    for (int off = 32; off; off >>= 1) { sl += __shfl_down(sl, off); sa += __shfl_down(sa, off); }
    if ((t & 63) == 0) { rl[t >> 6] = sl; ra[t >> 6] = sa; }
    __syncthreads();
    if (t == 0) {
        float L = rl[0] + rl[1] + rl[2] + rl[3];
        float A = ra[0] + ra[1] + ra[2] + ra[3];
        out[0] = (A > 0.f) ? (L / fmaxf(A, 1.f)) : 0.f;
    }
}

// ---------------- launch ----------------
extern "C" void kernel_launch(void* const* d_in, const int* in_sizes, int n_in,
                              void* d_out, int out_size, void* d_ws, size_t ws_size,
                              hipStream_t stream) {
    const float* clip   = (const float*)d_in[0];
    const float* gt     = (const float*)d_in[1];
    const float* conv_w = (const float*)d_in[2];
    const float* conv_b = (const float*)d_in[3];
    const float* cls_w  = (const float*)d_in[4];
    const float* cls_b  = (const float*)d_in[5];
    const float* reg_w  = (const float*)d_in[6];
    const float* reg_b  = (const float*)d_in[7];
    const float* w1     = (const float*)d_in[8];
    const float* b1     = (const float*)d_in[9];
    const float* w2     = (const float*)d_in[10];
    const float* b2     = (const float*)d_in[11];

    if (ws_size < WS_FLOATS * sizeof(float)) return;  // visible failure if ws too small

    float* ws  = (float*)d_ws;
    float* XP0 = ws + O_XP0;
    float* XP1 = ws + O_XP1;
    u16*   CH  = (u16*)(ws + O_CH);
    u16*   CL  = (u16*)(ws + O_CL);
    u16*   WHp = (u16*)(ws + O_WH);
    u16*   WLp = (u16*)(ws + O_WL);
    u16*   ZS  = (u16*)(ws + O_Z);
    float* HW  = ws + O_HW;
    float* SC  = ws + O_SC;
    float* RG  = ws + O_RG;
    float* ROI = ws + O_ROI;
    float* VAL = ws + O_VAL;
    float* LAB = ws + O_LAB;
    float* PO  = ws + O_PO;
    float* Hb  = ws + O_H;
    float* PR  = ws + O_PR;
    float* NF  = ws + O_NF;
    float* RL  = ws + O_RL;
    float* RA  = ws + O_RA;

    convert_all<<<NB_CLIP + NB_W + NB_Z + NB_HW, 256, 0, stream>>>(
        clip, conv_w, cls_w, reg_w, CH, CL, WHp, WLp, ZS, HW);
    conv_mfma<<<512, 256, 0, stream>>>(CH, CL, WHp, WLp, ZS, XP0, XP1);
    heads_kernel<<<NPOS, 64, 0, stream>>>(XP0, XP1, conv_b, HW, cls_b, reg_b, SC, RG);
    topk_nms<<<BATCH, 256, 0, stream>>>(SC, RG, ROI, VAL);
    align_labels<<<2 * NROI, 256, 0, stream>>>(clip, gt, ROI, PO, LAB);
    fc_kernel<1024><<<NROI / 4, 256, 0, stream>>>(PO, w1, b1, Hb, 1);
    fc_kernel<256><<<NROI / 4, 256, 0, stream>>>(Hb, w2, b2, PR, 0);
    normalize_rows<<<NROI, 256, 0, stream>>>(PR, NF);
    supcon_rows<<<NROI, 256, 0, stream>>>(NF, LAB, VAL, RL, RA);
    final_reduce<<<1, 256, 0, stream>>>(RL, RA, (float*)d_out);
}